// Round 3
// baseline (3104.968 us; speedup 1.0000x reference)
//
#include <hip/hip_runtime.h>
#include <cstdint>

#define NN 100000
#define EE 3200000
#define NPB 64                      // nodes per bucket
#define NB ((NN + NPB - 1) / NPB)   // 1563 buckets

// ---------------- bucket build ----------------

__global__ void k_hist_bucket(const int* __restrict__ dst, int* __restrict__ bcnt) {
    int e = blockIdx.x * blockDim.x + threadIdx.x;
    if (e < EE) atomicAdd(&bcnt[dst[e] >> 6], 1);
}

// single-block exclusive scan over NB (<=2048) bucket counts
__global__ void k_scan_buckets(const int* __restrict__ bcnt,
                               int* __restrict__ bucketptr,
                               int* __restrict__ cursor) {
    __shared__ int sm[1024];
    __shared__ int carry_sm;
    int i = threadIdx.x;

    // chunk 0: elements 0..1023
    int v0 = (i < NB) ? bcnt[i] : 0;
    sm[i] = v0;
    __syncthreads();
    for (int o = 1; o < 1024; o <<= 1) {
        int a = (i >= o) ? sm[i - o] : 0;
        __syncthreads();
        sm[i] += a;
        __syncthreads();
    }
    int incl0 = sm[i];
    if (i < NB) {
        bucketptr[i] = incl0 - v0;   // exclusive
        cursor[i]    = incl0 - v0;
    }
    if (i == 1023) carry_sm = incl0;
    __syncthreads();
    int carry = carry_sm;
    __syncthreads();

    // chunk 1: elements 1024..2047
    int j = 1024 + i;
    int v1 = (j < NB) ? bcnt[j] : 0;
    sm[i] = v1;
    __syncthreads();
    for (int o = 1; o < 1024; o <<= 1) {
        int a = (i >= o) ? sm[i - o] : 0;
        __syncthreads();
        sm[i] += a;
        __syncthreads();
    }
    int incl1 = carry + sm[i];
    if (j < NB) {
        bucketptr[j] = incl1 - v1;
        cursor[j]    = incl1 - v1;
    }
    if (i == 1023) bucketptr[NB] = incl1;   // total = EE
}

__global__ void k_scatter_bucket(const int* __restrict__ src, const int* __restrict__ dst,
                                 int* __restrict__ cursor, int* __restrict__ edges) {
    int e = blockIdx.x * blockDim.x + threadIdx.x;
    if (e < EE) {
        int d = dst[e];
        int b = d >> 6;
        int p = atomicAdd(&cursor[b], 1);
        edges[p] = src[e] | ((d & 63) << 17);   // src < 2^17
    }
}

// ---------------- GNN compute ----------------

// h[N,din] -> t = h@Wn ; hout = h@Ws + bn  (self term staged, neighbors added later)
__global__ void k_transform(const float* __restrict__ h,
                            const float* __restrict__ Wn,
                            const float* __restrict__ Ws,
                            const float* __restrict__ bn,
                            float* __restrict__ t,
                            float* __restrict__ hout,
                            int din) {
    __shared__ float WnL[128 * 32];
    __shared__ float WsL[128 * 32];
    for (int i = threadIdx.x; i < din * 32; i += 256) {
        WnL[i] = Wn[i];
        WsL[i] = Ws[i];
    }
    __syncthreads();
    int node = blockIdx.x * 8 + (threadIdx.x >> 5);
    int d = threadIdx.x & 31;
    if (node >= NN) return;
    const float* hr = h + (size_t)node * din;
    float accn = 0.f;
    float accs = bn[d];
    for (int k = 0; k < din; ++k) {
        float f = hr[k];
        accn += f * WnL[k * 32 + d];
        accs += f * WsL[k * 32 + d];
    }
    t[node * 32 + d] = accn;
    hout[node * 32 + d] = accs;
}

// one block per bucket: acc[64][32] in LDS, then hout = relu(hout + acc)
__global__ void k_agg(const int* __restrict__ bucketptr,
                      const int* __restrict__ edges,
                      const float* __restrict__ t,
                      float* __restrict__ hout) {
    __shared__ float acc[NPB * 32];
    int b = blockIdx.x;
    for (int i = threadIdx.x; i < NPB * 32; i += 256) acc[i] = 0.f;
    __syncthreads();
    int e0 = bucketptr[b];
    int e1 = bucketptr[b + 1];
    int d = threadIdx.x & 31;
    for (int j = e0 + (threadIdx.x >> 5); j < e1; j += 8) {
        int p = edges[j];
        int s = p & 0x1FFFF;
        int dl = p >> 17;
        atomicAdd(&acc[dl * 32 + d], t[s * 32 + d]);
    }
    __syncthreads();
    int base = b * NPB;
    for (int i = threadIdx.x; i < NPB * 32; i += 256) {
        int node = base + (i >> 5);
        if (node < NN) {
            int idx = node * 32 + (i & 31);
            hout[idx] = fmaxf(hout[idx] + acc[i], 0.f);
        }
    }
}

// concat(x,h1,h2,h3) @ fc_w + fc_b -> log_softmax
__global__ void k_final(const float* __restrict__ x,
                        const float* __restrict__ h1,
                        const float* __restrict__ h2,
                        const float* __restrict__ h3,
                        const float* __restrict__ fc_w,
                        const float* __restrict__ fc_b,
                        float* __restrict__ out) {
    __shared__ float Wl[224 * 10];
    __shared__ float bl[10];
    for (int i = threadIdx.x; i < 224 * 10; i += blockDim.x) Wl[i] = fc_w[i];
    if (threadIdx.x < 10) bl[threadIdx.x] = fc_b[threadIdx.x];
    __syncthreads();
    int n = blockIdx.x * blockDim.x + threadIdx.x;
    if (n >= NN) return;
    float acc[10];
    #pragma unroll
    for (int c = 0; c < 10; ++c) acc[c] = bl[c];
    const float* xr = x + (size_t)n * 128;
    for (int j = 0; j < 128; ++j) {
        float f = xr[j];
        #pragma unroll
        for (int c = 0; c < 10; ++c) acc[c] += f * Wl[j * 10 + c];
    }
    const float* hs[3] = {h1, h2, h3};
    for (int l = 0; l < 3; ++l) {
        const float* hr = hs[l] + (size_t)n * 32;
        for (int j = 0; j < 32; ++j) {
            float f = hr[j];
            #pragma unroll
            for (int c = 0; c < 10; ++c) acc[c] += f * Wl[(128 + l * 32 + j) * 10 + c];
        }
    }
    float m = acc[0];
    #pragma unroll
    for (int c = 1; c < 10; ++c) m = fmaxf(m, acc[c]);
    float s = 0.f;
    #pragma unroll
    for (int c = 0; c < 10; ++c) s += __expf(acc[c] - m);
    float ls = __logf(s);
    #pragma unroll
    for (int c = 0; c < 10; ++c) out[n * 10 + c] = acc[c] - m - ls;
}

extern "C" void kernel_launch(void* const* d_in, const int* in_sizes, int n_in,
                              void* d_out, int out_size, void* d_ws, size_t ws_size,
                              hipStream_t stream) {
    const float* x   = (const float*)d_in[0];
    const int*   src = (const int*)d_in[1];
    const int*   dst = (const int*)d_in[2];
    const float* Wn[3] = {(const float*)d_in[3], (const float*)d_in[6], (const float*)d_in[9]};
    const float* bn[3] = {(const float*)d_in[4], (const float*)d_in[7], (const float*)d_in[10]};
    const float* Ws[3] = {(const float*)d_in[5], (const float*)d_in[8], (const float*)d_in[11]};
    const float* fc_w = (const float*)d_in[12];
    const float* fc_b = (const float*)d_in[13];
    float* out = (float*)d_out;

    // workspace layout
    char* w = (char*)d_ws;
    const size_t NF = (size_t)NN * 32;
    float* t   = (float*)w;                     w += NF * 4;          // 12.8 MB
    float* h1  = (float*)w;                     w += NF * 4;
    float* h2  = (float*)w;                     w += NF * 4;
    float* h3  = (float*)w;                     w += NF * 4;
    int* edges = (int*)w;                       w += (size_t)EE * 4;  // 12.8 MB
    int* bcnt      = (int*)w;                   w += (size_t)NB * 4;
    int* bucketptr = (int*)w;                   w += (size_t)(NB + 1) * 4;
    int* cursor    = (int*)w;                   w += (size_t)NB * 4;
    float* hbuf[3] = {h1, h2, h3};

    // ---- bucket build ----
    hipMemsetAsync(bcnt, 0, (size_t)NB * 4, stream);
    k_hist_bucket<<<(EE + 255) / 256, 256, 0, stream>>>(dst, bcnt);
    k_scan_buckets<<<1, 1024, 0, stream>>>(bcnt, bucketptr, cursor);
    k_scatter_bucket<<<(EE + 255) / 256, 256, 0, stream>>>(src, dst, cursor, edges);

    // ---- layers ----
    const int mm_blocks = (NN + 7) / 8;
    const float* hin = x;
    int din = 128;
    for (int l = 0; l < 3; ++l) {
        k_transform<<<mm_blocks, 256, 0, stream>>>(hin, Wn[l], Ws[l], bn[l], t, hbuf[l], din);
        k_agg<<<NB, 256, 0, stream>>>(bucketptr, edges, t, hbuf[l]);
        hin = hbuf[l];
        din = 32;
    }
    k_final<<<(NN + 255) / 256, 256, 0, stream>>>(x, h1, h2, h3, fc_w, fc_b, out);
}

// Round 4
// 963.644 us; speedup vs baseline: 3.2221x; 3.2221x over previous
//
#include <hip/hip_runtime.h>
#include <cstdint>

#define NN 100000
#define EE 3200000
#define NPB 64                      // nodes per bucket
#define NB ((NN + NPB - 1) / NPB)   // 1563 buckets

__device__ inline float4 add4(float4 a, float4 b) {
    return make_float4(a.x + b.x, a.y + b.y, a.z + b.z, a.w + b.w);
}

// ---------------- bucket build ----------------

// grid-stride LDS histogram of dst>>6, flushed once per block
__global__ void k_hist_bucket(const int* __restrict__ dst, int* __restrict__ bcnt) {
    __shared__ int h[NB];
    for (int i = threadIdx.x; i < NB; i += 256) h[i] = 0;
    __syncthreads();
    for (int e = blockIdx.x * 256 + threadIdx.x; e < EE; e += gridDim.x * 256)
        atomicAdd(&h[dst[e] >> 6], 1);
    __syncthreads();
    for (int i = threadIdx.x; i < NB; i += 256) {
        int v = h[i];
        if (v) atomicAdd(&bcnt[i], v);
    }
}

// single-block exclusive scan over NB (<=2048) bucket counts
__global__ void k_scan_buckets(const int* __restrict__ bcnt,
                               int* __restrict__ bucketptr,
                               int* __restrict__ cursor) {
    __shared__ int sm[1024];
    __shared__ int carry_sm;
    int i = threadIdx.x;

    int v0 = (i < NB) ? bcnt[i] : 0;
    sm[i] = v0;
    __syncthreads();
    for (int o = 1; o < 1024; o <<= 1) {
        int a = (i >= o) ? sm[i - o] : 0;
        __syncthreads();
        sm[i] += a;
        __syncthreads();
    }
    int incl0 = sm[i];
    if (i < NB) {
        bucketptr[i] = incl0 - v0;
        cursor[i]    = incl0 - v0;
    }
    if (i == 1023) carry_sm = incl0;
    __syncthreads();
    int carry = carry_sm;
    __syncthreads();

    int j = 1024 + i;
    int v1 = (j < NB) ? bcnt[j] : 0;
    sm[i] = v1;
    __syncthreads();
    for (int o = 1; o < 1024; o <<= 1) {
        int a = (i >= o) ? sm[i - o] : 0;
        __syncthreads();
        sm[i] += a;
        __syncthreads();
    }
    int incl1 = carry + sm[i];
    if (j < NB) {
        bucketptr[j] = incl1 - v1;
        cursor[j]    = incl1 - v1;
    }
    if (i == 1023) bucketptr[NB] = incl1;   // == EE
}

__global__ void k_scatter_bucket(const int* __restrict__ src, const int* __restrict__ dst,
                                 int* __restrict__ cursor, int* __restrict__ edges) {
    int e = blockIdx.x * blockDim.x + threadIdx.x;
    if (e < EE) {
        int d = dst[e];
        int b = d >> 6;
        int p = atomicAdd(&cursor[b], 1);
        edges[p] = src[e] | ((d & 63) << 17);   // src < 2^17
    }
}

// one block per bucket: counting-sort bucket edges by local node id -> per-node CSR
__global__ void k_bucket_sort(const int* __restrict__ bucketptr,
                              const int* __restrict__ edges,
                              int* __restrict__ csr_src,
                              int* __restrict__ rowptr) {
    __shared__ int hist[NPB];   // becomes exclusive offsets
    __shared__ int cur[NPB];
    int b = blockIdx.x;
    int e0 = bucketptr[b];
    int e1 = bucketptr[b + 1];
    if (threadIdx.x < NPB) hist[threadIdx.x] = 0;
    __syncthreads();
    for (int j = e0 + threadIdx.x; j < e1; j += 256)
        atomicAdd(&hist[edges[j] >> 17], 1);
    __syncthreads();
    if (threadIdx.x == 0) {
        int acc = 0;
        for (int i = 0; i < NPB; ++i) {
            int v = hist[i];
            hist[i] = acc;
            cur[i] = acc;
            acc += v;
        }
    }
    __syncthreads();
    int node = b * NPB + threadIdx.x;
    if (threadIdx.x < NPB && node < NN) rowptr[node] = e0 + hist[threadIdx.x];
    if (b == 0 && threadIdx.x == 0) rowptr[NN] = EE;
    for (int j = e0 + threadIdx.x; j < e1; j += 256) {
        int p = edges[j];
        int dl = p >> 17;
        int pos = atomicAdd(&cur[dl], 1);
        csr_src[e0 + pos] = p & 0x1FFFF;
    }
}

// ---------------- GNN compute ----------------

// h[N,din] -> t = h@Wn ; hout = h@Ws + bn
__global__ void k_transform(const float* __restrict__ h,
                            const float* __restrict__ Wn,
                            const float* __restrict__ Ws,
                            const float* __restrict__ bn,
                            float* __restrict__ t,
                            float* __restrict__ hout,
                            int din) {
    __shared__ float WnL[128 * 32];
    __shared__ float WsL[128 * 32];
    for (int i = threadIdx.x; i < din * 32; i += 256) {
        WnL[i] = Wn[i];
        WsL[i] = Ws[i];
    }
    __syncthreads();
    int node = blockIdx.x * 8 + (threadIdx.x >> 5);
    int d = threadIdx.x & 31;
    if (node >= NN) return;
    const float* hr = h + (size_t)node * din;
    float accn = 0.f;
    float accs = bn[d];
    for (int k = 0; k < din; ++k) {
        float f = hr[k];
        accn += f * WnL[k * 32 + d];
        accs += f * WsL[k * 32 + d];
    }
    t[node * 32 + d] = accn;
    hout[node * 32 + d] = accs;
}

// 8 lanes per node, float4 per lane, 4-deep unroll: hout = relu(hout + seg_sum(t))
__global__ void k_aggregate(const int* __restrict__ rowptr,
                            const int* __restrict__ csr_src,
                            const float4* __restrict__ t4,
                            float4* __restrict__ hout4) {
    int node = blockIdx.x * 32 + (threadIdx.x >> 3);
    int q = threadIdx.x & 7;
    if (node >= NN) return;
    int j = rowptr[node];
    int end = rowptr[node + 1];
    float4 a0 = make_float4(0.f, 0.f, 0.f, 0.f);
    float4 a1 = a0, a2 = a0, a3 = a0;
    for (; j + 4 <= end; j += 4) {
        int s0 = csr_src[j];
        int s1 = csr_src[j + 1];
        int s2 = csr_src[j + 2];
        int s3 = csr_src[j + 3];
        a0 = add4(a0, t4[s0 * 8 + q]);
        a1 = add4(a1, t4[s1 * 8 + q]);
        a2 = add4(a2, t4[s2 * 8 + q]);
        a3 = add4(a3, t4[s3 * 8 + q]);
    }
    for (; j < end; ++j) a0 = add4(a0, t4[csr_src[j] * 8 + q]);
    float4 s = add4(add4(a0, a1), add4(a2, a3));
    int idx = node * 8 + q;
    float4 h = hout4[idx];
    h.x = fmaxf(h.x + s.x, 0.f);
    h.y = fmaxf(h.y + s.y, 0.f);
    h.z = fmaxf(h.z + s.z, 0.f);
    h.w = fmaxf(h.w + s.w, 0.f);
    hout4[idx] = h;
}

// concat(x,h1,h2,h3) @ fc_w + fc_b -> log_softmax
__global__ void k_final(const float* __restrict__ x,
                        const float* __restrict__ h1,
                        const float* __restrict__ h2,
                        const float* __restrict__ h3,
                        const float* __restrict__ fc_w,
                        const float* __restrict__ fc_b,
                        float* __restrict__ out) {
    __shared__ float Wl[224 * 10];
    __shared__ float bl[10];
    for (int i = threadIdx.x; i < 224 * 10; i += blockDim.x) Wl[i] = fc_w[i];
    if (threadIdx.x < 10) bl[threadIdx.x] = fc_b[threadIdx.x];
    __syncthreads();
    int n = blockIdx.x * blockDim.x + threadIdx.x;
    if (n >= NN) return;
    float acc[10];
    #pragma unroll
    for (int c = 0; c < 10; ++c) acc[c] = bl[c];
    const float* xr = x + (size_t)n * 128;
    for (int j = 0; j < 128; ++j) {
        float f = xr[j];
        #pragma unroll
        for (int c = 0; c < 10; ++c) acc[c] += f * Wl[j * 10 + c];
    }
    const float* hs[3] = {h1, h2, h3};
    for (int l = 0; l < 3; ++l) {
        const float* hr = hs[l] + (size_t)n * 32;
        for (int j = 0; j < 32; ++j) {
            float f = hr[j];
            #pragma unroll
            for (int c = 0; c < 10; ++c) acc[c] += f * Wl[(128 + l * 32 + j) * 10 + c];
        }
    }
    float m = acc[0];
    #pragma unroll
    for (int c = 1; c < 10; ++c) m = fmaxf(m, acc[c]);
    float s = 0.f;
    #pragma unroll
    for (int c = 0; c < 10; ++c) s += __expf(acc[c] - m);
    float ls = __logf(s);
    #pragma unroll
    for (int c = 0; c < 10; ++c) out[n * 10 + c] = acc[c] - m - ls;
}

extern "C" void kernel_launch(void* const* d_in, const int* in_sizes, int n_in,
                              void* d_out, int out_size, void* d_ws, size_t ws_size,
                              hipStream_t stream) {
    const float* x   = (const float*)d_in[0];
    const int*   src = (const int*)d_in[1];
    const int*   dst = (const int*)d_in[2];
    const float* Wn[3] = {(const float*)d_in[3], (const float*)d_in[6], (const float*)d_in[9]};
    const float* bn[3] = {(const float*)d_in[4], (const float*)d_in[7], (const float*)d_in[10]};
    const float* Ws[3] = {(const float*)d_in[5], (const float*)d_in[8], (const float*)d_in[11]};
    const float* fc_w = (const float*)d_in[12];
    const float* fc_b = (const float*)d_in[13];
    float* out = (float*)d_out;

    // workspace layout (edges aliases h3: edges dead before h3 is first written)
    char* w = (char*)d_ws;
    const size_t NF = (size_t)NN * 32;
    float* t   = (float*)w;                     w += NF * 4;          // 12.8 MB
    float* h1  = (float*)w;                     w += NF * 4;
    float* h2  = (float*)w;                     w += NF * 4;
    float* h3  = (float*)w;                     w += NF * 4;
    int* csr_src = (int*)w;                     w += (size_t)EE * 4;  // 12.8 MB
    int* bcnt      = (int*)w;                   w += (size_t)NB * 4;
    int* bucketptr = (int*)w;                   w += (size_t)(NB + 1) * 4;
    int* cursor    = (int*)w;                   w += (size_t)NB * 4;
    int* rowptr    = (int*)w;                   w += (size_t)(NN + 1) * 4;
    int* edges = (int*)h3;   // temp, dead before layer-2 transform writes h3
    float* hbuf[3] = {h1, h2, h3};

    // ---- CSR build (bucket scatter + within-bucket counting sort) ----
    hipMemsetAsync(bcnt, 0, (size_t)NB * 4, stream);
    k_hist_bucket<<<512, 256, 0, stream>>>(dst, bcnt);
    k_scan_buckets<<<1, 1024, 0, stream>>>(bcnt, bucketptr, cursor);
    k_scatter_bucket<<<(EE + 255) / 256, 256, 0, stream>>>(src, dst, cursor, edges);
    k_bucket_sort<<<NB, 256, 0, stream>>>(bucketptr, edges, csr_src, rowptr);

    // ---- layers ----
    const int mm_blocks = (NN + 7) / 8;
    const int ag_blocks = (NN + 31) / 32;
    const float* hin = x;
    int din = 128;
    for (int l = 0; l < 3; ++l) {
        k_transform<<<mm_blocks, 256, 0, stream>>>(hin, Wn[l], Ws[l], bn[l], t, hbuf[l], din);
        k_aggregate<<<ag_blocks, 256, 0, stream>>>(rowptr, csr_src, (const float4*)t, (float4*)hbuf[l]);
        hin = hbuf[l];
        din = 32;
    }
    k_final<<<(NN + 255) / 256, 256, 0, stream>>>(x, h1, h2, h3, fc_w, fc_b, out);
}